// Round 1
// baseline (307.761 us; speedup 1.0000x reference)
//
#include <hip/hip_runtime.h>
#include <hip/hip_fp16.h>

#define B_ 256
#define N_ 192
#define D_ 512
#define E_ 1024
#define H_ 512
#define K_ 58
#define M_ (B_*K_)   // 14848 = 64*232

typedef _Float16 f16;
typedef _Float16 half8 __attribute__((ext_vector_type(8)));
typedef float floatx4 __attribute__((ext_vector_type(4)));

__device__ inline half8 cvt8(float4 f0, float4 f1) {
  half8 r;
  r[0]=(f16)f0.x; r[1]=(f16)f0.y; r[2]=(f16)f0.z; r[3]=(f16)f0.w;
  r[4]=(f16)f1.x; r[5]=(f16)f1.y; r[6]=(f16)f1.z; r[7]=(f16)f1.w;
  return r;
}

// ---------------- top-K selection (rank-based, matches lax.top_k tie-break) ----
__global__ void topk_kernel(const float* __restrict__ attn, int* __restrict__ idx) {
  __shared__ float sv[N_];
  __shared__ int cnt;
  int b = blockIdx.x;
  int t = threadIdx.x;
  if (t == 0) cnt = 0;
  if (t < N_) sv[t] = attn[(size_t)b*193*193 + 1 + t];
  __syncthreads();
  if (t < N_) {
    float v = sv[t];
    int rank = 0;
    for (int j = 0; j < N_; ++j) {
      float vj = sv[j];
      rank += (vj > v) || (vj == v && j < t);
    }
    if (rank < K_) {
      int pos = atomicAdd(&cnt, 1);
      idx[b*K_ + pos] = t;     // order within the K slots is irrelevant (max/BN invariant)
    }
  }
}

// ---------------- gather + L2 normalize + f16 round: one wave per row --------
__global__ void gather_norm_kernel(const float* __restrict__ emb, const int* __restrict__ idx,
                                   f16* __restrict__ base) {
  int bk = blockIdx.x;
  int lane = threadIdx.x;      // 64 threads = 1 wave
  int b = bk / K_;
  int row = idx[bk];
  const float* src = emb + (size_t)b*N_*D_ + (size_t)row*D_ + lane*8;
  float4 v0 = ((const float4*)src)[0];
  float4 v1 = ((const float4*)src)[1];
  float s = v0.x*v0.x + v0.y*v0.y + v0.z*v0.z + v0.w*v0.w
          + v1.x*v1.x + v1.y*v1.y + v1.z*v1.z + v1.w*v1.w;
  #pragma unroll
  for (int off = 32; off > 0; off >>= 1) s += __shfl_xor(s, off);
  float norm = sqrtf(s) + 1e-8f;
  half8 o;
  o[0]=(f16)(v0.x/norm); o[1]=(f16)(v0.y/norm); o[2]=(f16)(v0.z/norm); o[3]=(f16)(v0.w/norm);
  o[4]=(f16)(v1.x/norm); o[5]=(f16)(v1.y/norm); o[6]=(f16)(v1.z/norm); o[7]=(f16)(v1.w/norm);
  *((uint4*)(base + (size_t)bk*D_ + lane*8)) = *(uint4*)&o;
}

// ---------------- GEMM1: h = base @ W1^T + b1  (M x 512, f32 out) ------------
__launch_bounds__(256)
__global__ void gemm1_kernel(const f16* __restrict__ base, const float* __restrict__ W1,
                             const float* __restrict__ b1, float* __restrict__ h) {
  __shared__ f16 sA[64*32];
  __shared__ f16 sB[64*32];
  int t = threadIdx.x;
  int m0 = blockIdx.x * 64;
  int n0 = blockIdx.y * 64;
  int row = t >> 2, seg = t & 3;
  int lane = t & 63, w = t >> 6, lm = lane & 15, quad = lane >> 4;
  floatx4 acc[4] = {};
  for (int k0 = 0; k0 < D_; k0 += 32) {
    *(uint4*)&sA[row*32 + seg*8] = *(const uint4*)(base + (size_t)(m0+row)*D_ + k0 + seg*8);
    const float* wsrc = W1 + (size_t)(n0+row)*D_ + k0 + seg*8;
    half8 hb = cvt8(((const float4*)wsrc)[0], ((const float4*)wsrc)[1]);
    *(uint4*)&sB[row*32 + seg*8] = *(uint4*)&hb;
    __syncthreads();
    half8 a = *(const half8*)&sA[(16*w + lm)*32 + quad*8];
    #pragma unroll
    for (int ct = 0; ct < 4; ++ct) {
      half8 bf = *(const half8*)&sB[(16*ct + lm)*32 + quad*8];
      acc[ct] = __builtin_amdgcn_mfma_f32_16x16x32_f16(a, bf, acc[ct], 0, 0, 0);
    }
    __syncthreads();
  }
  #pragma unroll
  for (int ct = 0; ct < 4; ++ct) {
    int col = n0 + 16*ct + lm;
    float bias = b1[col];
    #pragma unroll
    for (int r = 0; r < 4; ++r) {
      int grow = m0 + 16*w + quad*4 + r;   // C/D: col=lane&15, row=quad*4+r (m89-verified)
      h[(size_t)grow*H_ + col] = acc[ct][r] + bias;
    }
  }
}

// ---------------- column sums for BN stats ------------------------------------
__global__ void stats_kernel(const float* __restrict__ h, float* __restrict__ csum,
                             float* __restrict__ css) {
  int j = blockIdx.x*256 + threadIdx.x;
  int m0 = blockIdx.y*256;
  float s = 0.f, ss = 0.f;
  for (int m = m0; m < m0+256; ++m) {
    float v = h[(size_t)m*H_ + j];
    s += v; ss += v*v;
  }
  atomicAdd(&csum[j], s);
  atomicAdd(&css[j], ss);
}

__global__ void bnparam_kernel(const float* __restrict__ csum, const float* __restrict__ css,
                               const float* __restrict__ gamma, const float* __restrict__ beta,
                               float* __restrict__ scale, float* __restrict__ shift) {
  int j = blockIdx.x*256 + threadIdx.x;
  if (j < H_) {
    float mu  = csum[j] * (1.0f/M_);
    float var = css[j] * (1.0f/M_) - mu*mu;
    float sc  = gamma[j] / sqrtf(var + 1e-5f);
    scale[j] = sc;
    shift[j] = beta[j] - mu*sc;
  }
}

// ---- fused: feats[b,k,e] = [base ; relu(bn(h))] @ [Wfc ; W2]^T, max over k ---
__launch_bounds__(256)
__global__ void fused_kernel(const f16* __restrict__ base, const float* __restrict__ h,
                             const float* __restrict__ Wfc, const float* __restrict__ W2,
                             const float* __restrict__ bfc, const float* __restrict__ b2,
                             const float* __restrict__ scale, const float* __restrict__ shift,
                             float* __restrict__ out) {
  __shared__ f16 sA[64*32];
  __shared__ f16 sB[128*32];
  __shared__ float sScale[H_], sShift[H_];
  __shared__ float sMax[4*128];
  int t = threadIdx.x;
  int e0 = blockIdx.x * 128;
  int b  = blockIdx.y;
  for (int j = t; j < H_; j += 256) { sScale[j] = scale[j]; sShift[j] = shift[j]; }
  int row = t >> 2, seg = t & 3;
  int lane = t & 63, w = t >> 6, lm = lane & 15, quad = lane >> 4;
  floatx4 acc[8] = {};
  __syncthreads();
  for (int c0 = 0; c0 < D_ + H_; c0 += 32) {
    // ---- stage A (64 rows = K-dim padded to 64; rows >=58 are zero) ----
    uint4 av; av.x = 0u; av.y = 0u; av.z = 0u; av.w = 0u;
    if (c0 < D_) {
      if (row < K_) av = *(const uint4*)(base + ((size_t)b*K_ + row)*D_ + c0 + seg*8);
    } else {
      if (row < K_) {
        int j0 = (c0 - D_) + seg*8;
        const float* hs = h + ((size_t)b*K_ + row)*H_ + j0;
        float4 f0 = ((const float4*)hs)[0];
        float4 f1 = ((const float4*)hs)[1];
        float vals[8] = {f0.x,f0.y,f0.z,f0.w,f1.x,f1.y,f1.z,f1.w};
        half8 r;
        #pragma unroll
        for (int i = 0; i < 8; ++i) {
          float x = fmaxf(vals[i]*sScale[j0+i] + sShift[j0+i], 0.f);
          r[i] = (f16)x;
        }
        av = *(uint4*)&r;
      }
    }
    *(uint4*)&sA[row*32 + seg*8] = av;
    // ---- stage B (128 e-rows, two per thread) ----
    #pragma unroll
    for (int rr = 0; rr < 2; ++rr) {
      int br = row + 64*rr;
      const float* wsrc = (c0 < D_) ? (Wfc + (size_t)(e0+br)*D_ + c0 + seg*8)
                                    : (W2  + (size_t)(e0+br)*H_ + (c0-D_) + seg*8);
      half8 hb = cvt8(((const float4*)wsrc)[0], ((const float4*)wsrc)[1]);
      *(uint4*)&sB[br*32 + seg*8] = *(uint4*)&hb;
    }
    __syncthreads();
    half8 a = *(const half8*)&sA[(16*w + lm)*32 + quad*8];
    #pragma unroll
    for (int ct = 0; ct < 8; ++ct) {
      half8 bf = *(const half8*)&sB[(16*ct + lm)*32 + quad*8];
      acc[ct] = __builtin_amdgcn_mfma_f32_16x16x32_f16(a, bf, acc[ct], 0, 0, 0);
    }
    __syncthreads();
  }
  // ---- epilogue: max over k (mask padded rows), then cross-wave reduce ----
  #pragma unroll
  for (int ct = 0; ct < 8; ++ct) {
    float mx = -3.0e38f;
    #pragma unroll
    for (int r = 0; r < 4; ++r) {
      int krow = 16*w + quad*4 + r;
      if (krow < K_) mx = fmaxf(mx, acc[ct][r]);
    }
    mx = fmaxf(mx, __shfl_xor(mx, 16));
    mx = fmaxf(mx, __shfl_xor(mx, 32));
    if (lane < 16) sMax[w*128 + ct*16 + lm] = mx;
  }
  __syncthreads();
  if (t < 128) {
    float mx = fmaxf(fmaxf(sMax[t], sMax[128+t]), fmaxf(sMax[256+t], sMax[384+t]));
    int e = e0 + t;
    out[(size_t)b*E_ + e] = mx + bfc[e] + b2[e];
  }
}

extern "C" void kernel_launch(void* const* d_in, const int* in_sizes, int n_in,
                              void* d_out, int out_size, void* d_ws, size_t ws_size,
                              hipStream_t stream) {
  const float* emb   = (const float*)d_in[0];
  const float* attn  = (const float*)d_in[1];
  const float* Wfc   = (const float*)d_in[2];
  const float* bfc   = (const float*)d_in[3];
  const float* W1    = (const float*)d_in[4];
  const float* b1    = (const float*)d_in[5];
  const float* gamma = (const float*)d_in[6];
  const float* beta  = (const float*)d_in[7];
  const float* W2    = (const float*)d_in[8];
  const float* b2    = (const float*)d_in[9];
  float* out = (float*)d_out;

  char* ws = (char*)d_ws;
  int*   idx   = (int*)(ws + 0);            // 59392 B
  f16*   base  = (f16*)(ws + 59392);        // 15204352 B
  float* h     = (float*)(ws + 15263744);   // 30408704 B
  float* csum  = (float*)(ws + 45672448);   // 2048 B
  float* css   = (float*)(ws + 45674496);   // 2048 B
  float* scale = (float*)(ws + 45676544);   // 2048 B
  float* shift = (float*)(ws + 45678592);   // 2048 B

  hipMemsetAsync(csum, 0, 4096, stream);    // zero csum+css (ws is 0xAA-poisoned)

  topk_kernel<<<B_, 192, 0, stream>>>(attn, idx);
  gather_norm_kernel<<<M_, 64, 0, stream>>>(emb, idx, base);
  gemm1_kernel<<<dim3(M_/64, H_/64), 256, 0, stream>>>(base, W1, b1, h);
  stats_kernel<<<dim3(2, 58), 256, 0, stream>>>(h, csum, css);
  bnparam_kernel<<<2, 256, 0, stream>>>(csum, css, gamma, beta, scale, shift);
  fused_kernel<<<dim3(E_/128, B_), 256, 0, stream>>>(base, h, Wfc, W2, bfc, b2, scale, shift, out);
}

// Round 2
// 271.735 us; speedup vs baseline: 1.1326x; 1.1326x over previous
//
#include <hip/hip_runtime.h>
#include <hip/hip_fp16.h>

#define B_ 256
#define N_ 192
#define D_ 512
#define E_ 1024
#define H_ 512
#define K_ 58
#define M_ (B_*K_)      // 14848 real rows
#define M2_ (B_*64)     // 16384 padded rows (64 per batch, rows 58-63 zero)

typedef _Float16 f16;
typedef unsigned int u32;
typedef _Float16 half8 __attribute__((ext_vector_type(8)));
typedef float floatx4 __attribute__((ext_vector_type(4)));

__device__ inline half8 cvt8(float4 f0, float4 f1) {
  half8 r;
  r[0]=(f16)f0.x; r[1]=(f16)f0.y; r[2]=(f16)f0.z; r[3]=(f16)f0.w;
  r[4]=(f16)f1.x; r[5]=(f16)f1.y; r[6]=(f16)f1.z; r[7]=(f16)f1.w;
  return r;
}

// async global->LDS, 16B per lane; LDS dest = uniform base + lane*16
__device__ inline void gl_lds16(const f16* g, f16* l) {
  __builtin_amdgcn_global_load_lds((const __attribute__((address_space(1))) u32*)g,
                                   (__attribute__((address_space(3))) u32*)l, 16, 0, 0);
}

// ---------- prep: convert weights to f16 once. Wcat[e] = [Wfc[e] ; W2[e]] ----
__global__ void prep_kernel(const float* __restrict__ Wfc, const float* __restrict__ W2,
                            const float* __restrict__ W1,
                            f16* __restrict__ Wcat, f16* __restrict__ W1_16) {
  int g = blockIdx.x*256 + threadIdx.x;
  if (blockIdx.x < 512) {               // Wcat: 1024x1024 f16
    int idx = g*8;
    int e = idx >> 10, c = idx & 1023;
    const float* src = (c < 512) ? (Wfc + (size_t)e*512 + c)
                                 : (W2  + (size_t)e*512 + (c-512));
    half8 o = cvt8(((const float4*)src)[0], ((const float4*)src)[1]);
    *(uint4*)(Wcat + idx) = *(uint4*)&o;
  } else {                              // W1_16: 512x512 f16
    int idx = (g - 512*256)*8;
    const float* src = W1 + idx;
    half8 o = cvt8(((const float4*)src)[0], ((const float4*)src)[1]);
    *(uint4*)(W1_16 + idx) = *(uint4*)&o;
  }
}

// ---------- topk + gather + L2norm + f16, writes A16 cols [0,512) -----------
__global__ void topk_gather_kernel(const float* __restrict__ attn,
                                   const float* __restrict__ emb,
                                   f16* __restrict__ A16) {
  __shared__ float sv[N_];
  __shared__ int sidx[K_];
  __shared__ int cnt;
  int b = blockIdx.x, t = threadIdx.x;
  if (t == 0) cnt = 0;
  if (t < N_) sv[t] = attn[(size_t)b*193*193 + 1 + t];
  __syncthreads();
  if (t < N_) {
    float v = sv[t]; int rank = 0;
    for (int j = 0; j < N_; ++j) {
      float vj = sv[j];
      rank += (vj > v) || (vj == v && j < t);   // lax.top_k stable tie-break
    }
    if (rank < K_) sidx[atomicAdd(&cnt, 1)] = t;  // slot order irrelevant (max/BN invariant)
  }
  __syncthreads();
  int w = t >> 6, lane = t & 63;
  for (int slot = w; slot < 64; slot += 4) {
    f16* dst = A16 + ((size_t)b*64 + slot)*1024 + lane*8;
    if (slot < K_) {
      const float* src = emb + ((size_t)b*N_ + sidx[slot])*D_ + lane*8;
      float4 v0 = ((const float4*)src)[0];
      float4 v1 = ((const float4*)src)[1];
      float s = v0.x*v0.x + v0.y*v0.y + v0.z*v0.z + v0.w*v0.w
              + v1.x*v1.x + v1.y*v1.y + v1.z*v1.z + v1.w*v1.w;
      #pragma unroll
      for (int off = 32; off > 0; off >>= 1) s += __shfl_xor(s, off);
      float inv = 1.0f / (sqrtf(s) + 1e-8f);
      half8 o;
      o[0]=(f16)(v0.x*inv); o[1]=(f16)(v0.y*inv); o[2]=(f16)(v0.z*inv); o[3]=(f16)(v0.w*inv);
      o[4]=(f16)(v1.x*inv); o[5]=(f16)(v1.y*inv); o[6]=(f16)(v1.z*inv); o[7]=(f16)(v1.w*inv);
      *(uint4*)dst = *(uint4*)&o;
    } else {
      uint4 z; z.x=0u; z.y=0u; z.z=0u; z.w=0u;
      *(uint4*)dst = z;   // pad rows zero
    }
  }
}

// ---------- gemm1: h16 = A16[:, :512] @ W1_16^T + b1, fused BN column stats --
__launch_bounds__(256)
__global__ void gemm1_kernel(const f16* __restrict__ A16, const f16* __restrict__ W1_16,
                             const float* __restrict__ b1, f16* __restrict__ h16,
                             float* __restrict__ csum, float* __restrict__ css) {
  __shared__ f16 sA[128*32];
  __shared__ f16 sB[128*32];
  __shared__ float sSum[4*128];
  __shared__ float sSS[4*128];
  int t = threadIdx.x;
  int m0 = blockIdx.x * 128;
  int n0 = blockIdx.y * 128;
  int lane = t & 63, w = t >> 6, lm = lane & 15, quad = lane >> 4;
  int lrow = lane >> 2, lseg = lane & 3;
  floatx4 acc[2][8] = {};
  const f16* Abase = A16 + (size_t)m0*1024;
  const f16* Bbase = W1_16 + (size_t)n0*512;
  for (int k0 = 0; k0 < 512; k0 += 32) {
    #pragma unroll
    for (int gi = 0; gi < 2; ++gi) {
      int g = w + gi*4;
      gl_lds16(Abase + (size_t)(g*16 + lrow)*1024 + k0 + lseg*8, &sA[g*512]);
      gl_lds16(Bbase + (size_t)(g*16 + lrow)*512  + k0 + lseg*8, &sB[g*512]);
    }
    __syncthreads();
    half8 a0 = *(const half8*)&sA[(w*32      + lm)*32 + quad*8];
    half8 a1 = *(const half8*)&sA[(w*32 + 16 + lm)*32 + quad*8];
    #pragma unroll
    for (int ct = 0; ct < 8; ++ct) {
      half8 bf = *(const half8*)&sB[(ct*16 + lm)*32 + quad*8];
      acc[0][ct] = __builtin_amdgcn_mfma_f32_16x16x32_f16(a0, bf, acc[0][ct], 0, 0, 0);
      acc[1][ct] = __builtin_amdgcn_mfma_f32_16x16x32_f16(a1, bf, acc[1][ct], 0, 0, 0);
    }
    __syncthreads();
  }
  // epilogue: write h16 (+bias), accumulate masked column stats
  #pragma unroll
  for (int ct = 0; ct < 8; ++ct) {
    int col = n0 + ct*16 + lm;
    float bias = b1[col];
    float s = 0.f, ss = 0.f;
    #pragma unroll
    for (int s2 = 0; s2 < 2; ++s2) {
      int rb = w*32 + s2*16 + quad*4;
      int rib = rb & 63;
      #pragma unroll
      for (int r = 0; r < 4; ++r) {
        float x = acc[s2][ct][r] + bias;
        h16[(size_t)(m0 + rb + r)*H_ + col] = (f16)x;
        if (rib + r < K_) { s += x; ss += x*x; }   // stats over real rows only
      }
    }
    s  += __shfl_xor(s, 16);  s  += __shfl_xor(s, 32);
    ss += __shfl_xor(ss, 16); ss += __shfl_xor(ss, 32);
    if (lane < 16) { sSum[w*128 + ct*16 + lm] = s; sSS[w*128 + ct*16 + lm] = ss; }
  }
  __syncthreads();
  if (t < 128) {
    float s  = sSum[t] + sSum[128+t] + sSum[256+t] + sSum[384+t];
    float ss = sSS[t]  + sSS[128+t]  + sSS[256+t]  + sSS[384+t];
    atomicAdd(&csum[n0 + t], s);
    atomicAdd(&css[n0 + t], ss);
  }
}

// ---------- bnrelu: A16[:, 512:1024] = relu(bn(h16)) as f16 ------------------
__global__ void bnrelu_kernel(const f16* __restrict__ h16, const float* __restrict__ csum,
                              const float* __restrict__ css, const float* __restrict__ gamma,
                              const float* __restrict__ beta, f16* __restrict__ A16) {
  int g = blockIdx.x*256 + threadIdx.x;   // one thread = 8 cols of one row
  int row = g >> 6;
  int c0 = (g & 63)*8;
  f16* dst = A16 + (size_t)row*1024 + 512 + c0;
  if ((row & 63) >= K_) {
    uint4 z; z.x=0u; z.y=0u; z.z=0u; z.w=0u;
    *(uint4*)dst = z;
    return;
  }
  half8 hv = *(const half8*)(h16 + (size_t)row*512 + c0);
  half8 o;
  #pragma unroll
  for (int i = 0; i < 8; ++i) {
    int j = c0 + i;
    float mu  = csum[j] * (1.0f/M_);
    float var = css[j] * (1.0f/M_) - mu*mu;
    float sc  = gamma[j] * rsqrtf(var + 1e-5f);
    float sh  = beta[j] - mu*sc;
    o[i] = (f16)fmaxf((float)hv[i]*sc + sh, 0.0f);
  }
  *(uint4*)dst = *(uint4*)&o;
}

// ---------- fused: C = A16 @ Wcat^T, max over k per batch, + biases ----------
__launch_bounds__(256)
__global__ void fused_kernel(const f16* __restrict__ A16, const f16* __restrict__ Wcat,
                             const float* __restrict__ bfc, const float* __restrict__ b2,
                             float* __restrict__ out) {
  __shared__ f16 sA[128*32];
  __shared__ f16 sB[128*32];
  __shared__ float sMax[4*128];
  int t = threadIdx.x;
  int e0 = blockIdx.x * 128;
  int lane = t & 63, w = t >> 6, lm = lane & 15, quad = lane >> 4;
  int lrow = lane >> 2, lseg = lane & 3;
  floatx4 acc[2][8] = {};
  const f16* Abase = A16 + (size_t)blockIdx.y*128*1024;   // 2 batches per block
  const f16* Bbase = Wcat + (size_t)e0*1024;
  for (int k0 = 0; k0 < 1024; k0 += 32) {
    #pragma unroll
    for (int gi = 0; gi < 2; ++gi) {
      int g = w + gi*4;
      gl_lds16(Abase + (size_t)(g*16 + lrow)*1024 + k0 + lseg*8, &sA[g*512]);
      gl_lds16(Bbase + (size_t)(g*16 + lrow)*1024 + k0 + lseg*8, &sB[g*512]);
    }
    __syncthreads();
    half8 a0 = *(const half8*)&sA[(w*32      + lm)*32 + quad*8];
    half8 a1 = *(const half8*)&sA[(w*32 + 16 + lm)*32 + quad*8];
    #pragma unroll
    for (int ct = 0; ct < 8; ++ct) {
      half8 bf = *(const half8*)&sB[(ct*16 + lm)*32 + quad*8];
      acc[0][ct] = __builtin_amdgcn_mfma_f32_16x16x32_f16(a0, bf, acc[0][ct], 0, 0, 0);
      acc[1][ct] = __builtin_amdgcn_mfma_f32_16x16x32_f16(a1, bf, acc[1][ct], 0, 0, 0);
    }
    __syncthreads();
  }
  // epilogue: masked max over k rows (per batch half), cross-wave reduce
  #pragma unroll
  for (int ct = 0; ct < 8; ++ct) {
    float mx = -3.0e38f;
    #pragma unroll
    for (int s2 = 0; s2 < 2; ++s2) {
      int rib = (w*32 + s2*16 + quad*4) & 63;
      #pragma unroll
      for (int r = 0; r < 4; ++r)
        if (rib + r < K_) mx = fmaxf(mx, acc[s2][ct][r]);
    }
    mx = fmaxf(mx, __shfl_xor(mx, 16));
    mx = fmaxf(mx, __shfl_xor(mx, 32));
    if (lane < 16) sMax[w*128 + ct*16 + lm] = mx;   // waves 0,1 -> b even; 2,3 -> b odd
  }
  __syncthreads();
  {
    int bb  = t >> 7;          // 0,1
    int col = t & 127;
    float mx = bb == 0 ? fmaxf(sMax[col], sMax[128+col])
                       : fmaxf(sMax[256+col], sMax[384+col]);
    int e = e0 + col;
    out[((size_t)blockIdx.y*2 + bb)*E_ + e] = mx + bfc[e] + b2[e];
  }
}

extern "C" void kernel_launch(void* const* d_in, const int* in_sizes, int n_in,
                              void* d_out, int out_size, void* d_ws, size_t ws_size,
                              hipStream_t stream) {
  const float* emb   = (const float*)d_in[0];
  const float* attn  = (const float*)d_in[1];
  const float* Wfc   = (const float*)d_in[2];
  const float* bfc   = (const float*)d_in[3];
  const float* W1    = (const float*)d_in[4];
  const float* b1    = (const float*)d_in[5];
  const float* gamma = (const float*)d_in[6];
  const float* beta  = (const float*)d_in[7];
  const float* W2    = (const float*)d_in[8];
  const float* b2    = (const float*)d_in[9];
  float* out = (float*)d_out;

  char* ws = (char*)d_ws;
  f16*   A16   = (f16*)(ws);                    // 16384*1024*2 = 33,554,432
  f16*   h16   = (f16*)(ws + 33554432);         // 16384*512*2  = 16,777,216
  f16*   Wcat  = (f16*)(ws + 50331648);         // 1024*1024*2  =  2,097,152
  f16*   W1_16 = (f16*)(ws + 52428800);         //  512*512*2   =    524,288
  float* csum  = (float*)(ws + 52953088);       // 2048
  float* css   = (float*)(ws + 52955136);       // 2048

  hipMemsetAsync(csum, 0, 4096, stream);        // zero csum+css

  prep_kernel<<<640, 256, 0, stream>>>(Wfc, W2, W1, Wcat, W1_16);
  topk_gather_kernel<<<B_, 256, 0, stream>>>(attn, emb, A16);
  gemm1_kernel<<<dim3(M2_/128, H_/128), 256, 0, stream>>>(A16, W1_16, b1, h16, csum, css);
  bnrelu_kernel<<<M2_*64/256, 256, 0, stream>>>(h16, csum, css, gamma, beta, A16);
  fused_kernel<<<dim3(E_/128, B_/2), 256, 0, stream>>>(A16, Wcat, bfc, b2, out);
}

// Round 3
// 266.799 us; speedup vs baseline: 1.1535x; 1.0185x over previous
//
#include <hip/hip_runtime.h>
#include <hip/hip_fp16.h>

#define B_ 256
#define N_ 192
#define D_ 512
#define E_ 1024
#define H_ 512
#define K_ 58
#define M_ (B_*K_)      // 14848 real rows
#define M2_ (B_*64)     // 16384 padded rows (64 per batch, rows 58-63 zero)

typedef _Float16 f16;
typedef unsigned int u32;
typedef _Float16 half8 __attribute__((ext_vector_type(8)));
typedef float floatx4 __attribute__((ext_vector_type(4)));

__device__ inline half8 cvt8(float4 f0, float4 f1) {
  half8 r;
  r[0]=(f16)f0.x; r[1]=(f16)f0.y; r[2]=(f16)f0.z; r[3]=(f16)f0.w;
  r[4]=(f16)f1.x; r[5]=(f16)f1.y; r[6]=(f16)f1.z; r[7]=(f16)f1.w;
  return r;
}

// async global->LDS, 16B/lane; LDS dest = wave-uniform base + lane*16
__device__ inline void gl_lds16(const f16* g, f16* l) {
  __builtin_amdgcn_global_load_lds((const __attribute__((address_space(1))) u32*)g,
                                   (__attribute__((address_space(3))) u32*)l, 16, 0, 0);
}

// ---------- setup: weight cvt + topk + gather + L2norm + stats-zero ---------
// blocks [0,512): Wcat = [Wfc;W2] f16   blocks [512,640): W1_16
// blocks [640,896): per-batch topk + gather -> A16 cols [0,512)
// block 896: zero csum/css
__global__ void setup_kernel(const float* __restrict__ Wfc, const float* __restrict__ W2,
                             const float* __restrict__ W1, const float* __restrict__ attn,
                             const float* __restrict__ emb,
                             f16* __restrict__ Wcat, f16* __restrict__ W1_16,
                             f16* __restrict__ A16, float* __restrict__ csum) {
  __shared__ float sv[N_];
  __shared__ int sidx[K_];
  __shared__ int cnt;
  int blk = blockIdx.x, t = threadIdx.x;
  if (blk < 512) {                      // Wcat: 1024x1024 f16
    int idx = (blk*256 + t)*8;
    int e = idx >> 10, c = idx & 1023;
    const float* src = (c < 512) ? (Wfc + (size_t)e*512 + c)
                                 : (W2  + (size_t)e*512 + (c-512));
    half8 o = cvt8(((const float4*)src)[0], ((const float4*)src)[1]);
    *(uint4*)(Wcat + idx) = *(uint4*)&o;
  } else if (blk < 640) {               // W1_16: 512x512 f16
    int idx = ((blk-512)*256 + t)*8;
    const float* src = W1 + idx;
    half8 o = cvt8(((const float4*)src)[0], ((const float4*)src)[1]);
    *(uint4*)(W1_16 + idx) = *(uint4*)&o;
  } else if (blk < 896) {               // topk + gather for batch b
    int b = blk - 640;
    if (t == 0) cnt = 0;
    if (t < N_) sv[t] = attn[(size_t)b*193*193 + 1 + t];
    __syncthreads();
    if (t < N_) {
      float v = sv[t]; int rank = 0;
      for (int j = 0; j < N_; ++j) {
        float vj = sv[j];
        rank += (vj > v) || (vj == v && j < t);   // lax.top_k stable tie-break
      }
      if (rank < K_) sidx[atomicAdd(&cnt, 1)] = t;  // slot order irrelevant (max/BN invariant)
    }
    __syncthreads();
    int w = t >> 6, lane = t & 63;
    for (int slot = w; slot < 64; slot += 4) {
      f16* dst = A16 + ((size_t)b*64 + slot)*1024 + lane*8;
      if (slot < K_) {
        const float* src = emb + ((size_t)b*N_ + sidx[slot])*D_ + lane*8;
        float4 v0 = ((const float4*)src)[0];
        float4 v1 = ((const float4*)src)[1];
        float s = v0.x*v0.x + v0.y*v0.y + v0.z*v0.z + v0.w*v0.w
                + v1.x*v1.x + v1.y*v1.y + v1.z*v1.z + v1.w*v1.w;
        #pragma unroll
        for (int off = 32; off > 0; off >>= 1) s += __shfl_xor(s, off);
        float inv = 1.0f / (sqrtf(s) + 1e-8f);
        half8 o;
        o[0]=(f16)(v0.x*inv); o[1]=(f16)(v0.y*inv); o[2]=(f16)(v0.z*inv); o[3]=(f16)(v0.w*inv);
        o[4]=(f16)(v1.x*inv); o[5]=(f16)(v1.y*inv); o[6]=(f16)(v1.z*inv); o[7]=(f16)(v1.w*inv);
        *(uint4*)dst = *(uint4*)&o;
      } else {
        uint4 z; z.x=0u; z.y=0u; z.z=0u; z.w=0u;
        *(uint4*)dst = z;   // pad rows zero
      }
    }
  } else {                              // zero csum(512)+css(512), contiguous
    float4 z; z.x=0.f; z.y=0.f; z.z=0.f; z.w=0.f;
    ((float4*)csum)[t] = z;
  }
}

// ---------- gemm1: A16[:,512:1024] = A16[:,0:512] @ W1_16^T + b1 (pre-BN h) --
// 64x128 tile (1 batch x 128 H-cols), BK=64 via two 32-wide LDS buffers.
__launch_bounds__(256)
__global__ void gemm1_kernel(const f16* __restrict__ A16, const f16* __restrict__ W1_16,
                             const float* __restrict__ b1, f16* __restrict__ Aout,
                             float* __restrict__ csum, float* __restrict__ css) {
  __shared__ f16 sA0[64*32], sA1[64*32];
  __shared__ f16 sB0[128*32], sB1[128*32];
  __shared__ float sSum[4*128], sSS[4*128];
  int t = threadIdx.x;
  int n0 = blockIdx.x * 128;
  int m0 = blockIdx.y * 64;
  int lane = t & 63, w = t >> 6, lm = lane & 15, quad = lane >> 4;
  int lrow = lane >> 2, lseg = lane & 3;
  floatx4 acc[8] = {};
  const f16* Ab = A16 + (size_t)m0*1024;
  const f16* Bb = W1_16 + (size_t)n0*512;
  for (int k0 = 0; k0 < 512; k0 += 64) {
    gl_lds16(Ab + (size_t)(w*16 + lrow)*1024 + k0      + lseg*8, &sA0[w*16*32]);
    gl_lds16(Ab + (size_t)(w*16 + lrow)*1024 + k0 + 32 + lseg*8, &sA1[w*16*32]);
    gl_lds16(Bb + (size_t)(w*16 + lrow)*512 + k0      + lseg*8, &sB0[w*16*32]);
    gl_lds16(Bb + (size_t)(w*16 + lrow)*512 + k0 + 32 + lseg*8, &sB1[w*16*32]);
    gl_lds16(Bb + (size_t)(64 + w*16 + lrow)*512 + k0      + lseg*8, &sB0[(64 + w*16)*32]);
    gl_lds16(Bb + (size_t)(64 + w*16 + lrow)*512 + k0 + 32 + lseg*8, &sB1[(64 + w*16)*32]);
    __syncthreads();
    half8 a0 = *(const half8*)&sA0[(w*16 + lm)*32 + quad*8];
    half8 a1 = *(const half8*)&sA1[(w*16 + lm)*32 + quad*8];
    #pragma unroll
    for (int ct = 0; ct < 8; ++ct) {
      half8 b0 = *(const half8*)&sB0[(ct*16 + lm)*32 + quad*8];
      acc[ct] = __builtin_amdgcn_mfma_f32_16x16x32_f16(a0, b0, acc[ct], 0, 0, 0);
      half8 b1f = *(const half8*)&sB1[(ct*16 + lm)*32 + quad*8];
      acc[ct] = __builtin_amdgcn_mfma_f32_16x16x32_f16(a1, b1f, acc[ct], 0, 0, 0);
    }
    __syncthreads();
  }
  // epilogue: write pre-BN h (f16, in-place right half of A16), masked stats
  #pragma unroll
  for (int ct = 0; ct < 8; ++ct) {
    int col = n0 + ct*16 + lm;
    float bias = b1[col];
    float s = 0.f, ss = 0.f;
    int rb = w*16 + quad*4;
    #pragma unroll
    for (int r = 0; r < 4; ++r) {
      float x = acc[ct][r] + bias;
      Aout[(size_t)(m0 + rb + r)*1024 + 512 + col] = (f16)x;
      if (rb + r < K_) { s += x; ss += x*x; }   // stats over real rows only
    }
    s  += __shfl_xor(s, 16);  s  += __shfl_xor(s, 32);
    ss += __shfl_xor(ss, 16); ss += __shfl_xor(ss, 32);
    if (lane < 16) { sSum[w*128 + ct*16 + lm] = s; sSS[w*128 + ct*16 + lm] = ss; }
  }
  __syncthreads();
  if (t < 128) {
    float s  = sSum[t] + sSum[128+t] + sSum[256+t] + sSum[384+t];
    float ss = sSS[t]  + sSS[128+t]  + sSS[256+t]  + sSS[384+t];
    atomicAdd(&csum[n0 + t], s);
    atomicAdd(&css[n0 + t], ss);
  }
}

// ---------- bnrelu (in place on A16 right half): x -> relu(x*sc + sh) --------
// 16 rows per block; scale/shift computed once into LDS.
__global__ void bnrelu_kernel(f16* __restrict__ A16, const float* __restrict__ csum,
                              const float* __restrict__ css, const float* __restrict__ gamma,
                              const float* __restrict__ beta) {
  __shared__ float sSc[H_], sSh[H_];
  int t = threadIdx.x;
  for (int j = t; j < H_; j += 256) {
    float mu  = csum[j] * (1.0f/M_);
    float var = css[j] * (1.0f/M_) - mu*mu;
    float sc  = gamma[j] * rsqrtf(var + 1e-5f);
    sSc[j] = sc;
    sSh[j] = beta[j] - mu*sc;
  }
  __syncthreads();
  int r0 = blockIdx.x * 16;
  #pragma unroll
  for (int i = 0; i < 4; ++i) {
    int seg = t + 256*i;                 // 16 rows x 64 col-segments
    int row = r0 + (seg >> 6);
    int c0  = (seg & 63) * 8;
    f16* p = A16 + (size_t)row*1024 + 512 + c0;
    if ((row & 63) >= K_) {
      uint4 z; z.x=0u; z.y=0u; z.z=0u; z.w=0u;
      *(uint4*)p = z;                    // pad rows must be zero (had +bias)
    } else {
      half8 hv = *(const half8*)p;
      half8 o;
      #pragma unroll
      for (int k = 0; k < 8; ++k)
        o[k] = (f16)fmaxf((float)hv[k]*sSc[c0+k] + sSh[c0+k], 0.0f);
      *(uint4*)p = *(uint4*)&o;
    }
  }
}

// ---------- fused: C = A16 @ Wcat^T, max over k per batch, + biases ----------
// 64x128 tile (1 batch per block), BK=64, grid (8 e-blocks, 256 batches).
__launch_bounds__(256)
__global__ void fused_kernel(const f16* __restrict__ A16, const f16* __restrict__ Wcat,
                             const float* __restrict__ bfc, const float* __restrict__ b2,
                             float* __restrict__ out) {
  __shared__ f16 sA0[64*32], sA1[64*32];
  __shared__ f16 sB0[128*32], sB1[128*32];
  __shared__ float sMax[4*128];
  int t = threadIdx.x;
  int e0 = blockIdx.x * 128;
  int b  = blockIdx.y;
  int lane = t & 63, w = t >> 6, lm = lane & 15, quad = lane >> 4;
  int lrow = lane >> 2, lseg = lane & 3;
  floatx4 acc[8] = {};
  const f16* Ab = A16 + (size_t)b*64*1024;
  const f16* Bb = Wcat + (size_t)e0*1024;
  for (int k0 = 0; k0 < 1024; k0 += 64) {
    gl_lds16(Ab + (size_t)(w*16 + lrow)*1024 + k0      + lseg*8, &sA0[w*16*32]);
    gl_lds16(Ab + (size_t)(w*16 + lrow)*1024 + k0 + 32 + lseg*8, &sA1[w*16*32]);
    gl_lds16(Bb + (size_t)(w*16 + lrow)*1024 + k0      + lseg*8, &sB0[w*16*32]);
    gl_lds16(Bb + (size_t)(w*16 + lrow)*1024 + k0 + 32 + lseg*8, &sB1[w*16*32]);
    gl_lds16(Bb + (size_t)(64 + w*16 + lrow)*1024 + k0      + lseg*8, &sB0[(64 + w*16)*32]);
    gl_lds16(Bb + (size_t)(64 + w*16 + lrow)*1024 + k0 + 32 + lseg*8, &sB1[(64 + w*16)*32]);
    __syncthreads();
    half8 a0 = *(const half8*)&sA0[(w*16 + lm)*32 + quad*8];
    half8 a1 = *(const half8*)&sA1[(w*16 + lm)*32 + quad*8];
    #pragma unroll
    for (int ct = 0; ct < 8; ++ct) {
      half8 b0 = *(const half8*)&sB0[(ct*16 + lm)*32 + quad*8];
      acc[ct] = __builtin_amdgcn_mfma_f32_16x16x32_f16(a0, b0, acc[ct], 0, 0, 0);
      half8 b1f = *(const half8*)&sB1[(ct*16 + lm)*32 + quad*8];
      acc[ct] = __builtin_amdgcn_mfma_f32_16x16x32_f16(a1, b1f, acc[ct], 0, 0, 0);
    }
    __syncthreads();
  }
  // epilogue: masked max over this batch's 58 real rows
  #pragma unroll
  for (int ct = 0; ct < 8; ++ct) {
    float mx = -3.0e38f;
    int rb = w*16 + quad*4;
    #pragma unroll
    for (int r = 0; r < 4; ++r)
      if (rb + r < K_) mx = fmaxf(mx, acc[ct][r]);
    mx = fmaxf(mx, __shfl_xor(mx, 16));
    mx = fmaxf(mx, __shfl_xor(mx, 32));
    if (lane < 16) sMax[w*128 + ct*16 + lm] = mx;
  }
  __syncthreads();
  if (t < 128) {
    float mx = fmaxf(fmaxf(sMax[t], sMax[128+t]), fmaxf(sMax[256+t], sMax[384+t]));
    int e = e0 + t;
    out[(size_t)b*E_ + e] = mx + bfc[e] + b2[e];
  }
}

extern "C" void kernel_launch(void* const* d_in, const int* in_sizes, int n_in,
                              void* d_out, int out_size, void* d_ws, size_t ws_size,
                              hipStream_t stream) {
  const float* emb   = (const float*)d_in[0];
  const float* attn  = (const float*)d_in[1];
  const float* Wfc   = (const float*)d_in[2];
  const float* bfc   = (const float*)d_in[3];
  const float* W1    = (const float*)d_in[4];
  const float* b1    = (const float*)d_in[5];
  const float* gamma = (const float*)d_in[6];
  const float* beta  = (const float*)d_in[7];
  const float* W2    = (const float*)d_in[8];
  const float* b2    = (const float*)d_in[9];
  float* out = (float*)d_out;

  char* ws = (char*)d_ws;
  f16*   A16   = (f16*)(ws);                    // 16384*1024*2 = 33,554,432 (right half = h then relu(bn(h)))
  f16*   Wcat  = (f16*)(ws + 33554432);         // 1024*1024*2  =  2,097,152
  f16*   W1_16 = (f16*)(ws + 35651584);         //  512*512*2   =    524,288
  float* csum  = (float*)(ws + 36175872);       // 2048
  float* css   = (float*)(ws + 36177920);       // 2048 (contiguous after csum)

  setup_kernel<<<897, 256, 0, stream>>>(Wfc, W2, W1, attn, emb, Wcat, W1_16, A16, csum);
  gemm1_kernel<<<dim3(H_/128, B_), 256, 0, stream>>>(A16, W1_16, b1, A16, csum, css);
  bnrelu_kernel<<<M2_/16, 256, 0, stream>>>(A16, csum, css, gamma, beta);
  fused_kernel<<<dim3(E_/128, B_), 256, 0, stream>>>(A16, Wcat, bfc, b2, out);
}

// Round 4
// 255.131 us; speedup vs baseline: 1.2063x; 1.0457x over previous
//
#include <hip/hip_runtime.h>
#include <hip/hip_fp16.h>

#define B_ 256
#define N_ 192
#define D_ 512
#define E_ 1024
#define H_ 512
#define K_ 58
#define M_ (B_*K_)      // 14848 real rows
#define M2_ (B_*64)     // 16384 padded rows (64 per batch, rows 58-63 zero)

typedef _Float16 f16;
typedef unsigned int u32;
typedef _Float16 half8 __attribute__((ext_vector_type(8)));
typedef float floatx4 __attribute__((ext_vector_type(4)));

__device__ inline half8 cvt8(float4 f0, float4 f1) {
  half8 r;
  r[0]=(f16)f0.x; r[1]=(f16)f0.y; r[2]=(f16)f0.z; r[3]=(f16)f0.w;
  r[4]=(f16)f1.x; r[5]=(f16)f1.y; r[6]=(f16)f1.z; r[7]=(f16)f1.w;
  return r;
}

// async global->LDS, 16B/lane; LDS dest = wave-uniform base + lane*16
__device__ inline void gl_lds16(const f16* g, f16* l) {
  __builtin_amdgcn_global_load_lds((const __attribute__((address_space(1))) u32*)g,
                                   (__attribute__((address_space(3))) u32*)l, 16, 0, 0);
}

// Stage a 128x32 f16 tile into sT with XOR swizzle: LDS slot (r, c') holds
// global chunk c = c' ^ ((r>>1)&3).  Lane l covers row R0+(l>>2), slot c'=l&3,
// so it fetches global chunk (l&3)^((l>>3)&3).  Conflict-free on read-back.
__device__ inline void stage128(const f16* gbase, int gstride, f16* sT, int w, int lane) {
  int lrow  = lane >> 2;
  int chunk = (lane & 3) ^ ((lane >> 3) & 3);
  gl_lds16(gbase + (size_t)(w*16      + lrow)*gstride + chunk*8, &sT[(w*16)*32]);
  gl_lds16(gbase + (size_t)(64 + w*16 + lrow)*gstride + chunk*8, &sT[(64 + w*16)*32]);
}

// ---------- setup: weight cvt + topk + gather + L2norm + stats-zero ---------
__global__ void setup_kernel(const float* __restrict__ Wfc, const float* __restrict__ W2,
                             const float* __restrict__ W1, const float* __restrict__ attn,
                             const float* __restrict__ emb,
                             f16* __restrict__ Wcat, f16* __restrict__ W1_16,
                             f16* __restrict__ A16, float* __restrict__ csum) {
  __shared__ float sv[N_];
  __shared__ int sidx[K_];
  __shared__ int cnt;
  int blk = blockIdx.x, t = threadIdx.x;
  if (blk < 512) {                      // Wcat = [Wfc;W2]: 1024x1024 f16
    int idx = (blk*256 + t)*8;
    int e = idx >> 10, c = idx & 1023;
    const float* src = (c < 512) ? (Wfc + (size_t)e*512 + c)
                                 : (W2  + (size_t)e*512 + (c-512));
    half8 o = cvt8(((const float4*)src)[0], ((const float4*)src)[1]);
    *(uint4*)(Wcat + idx) = *(uint4*)&o;
  } else if (blk < 640) {               // W1_16: 512x512 f16
    int idx = ((blk-512)*256 + t)*8;
    const float* src = W1 + idx;
    half8 o = cvt8(((const float4*)src)[0], ((const float4*)src)[1]);
    *(uint4*)(W1_16 + idx) = *(uint4*)&o;
  } else if (blk < 896) {               // topk + gather + L2norm for batch b
    int b = blk - 640;
    if (t == 0) cnt = 0;
    if (t < N_) sv[t] = attn[(size_t)b*193*193 + 1 + t];
    __syncthreads();
    if (t < N_) {
      float v = sv[t]; int rank = 0;
      for (int j = 0; j < N_; ++j) {
        float vj = sv[j];
        rank += (vj > v) || (vj == v && j < t);   // lax.top_k stable tie-break
      }
      if (rank < K_) sidx[atomicAdd(&cnt, 1)] = t;  // slot order irrelevant (max/BN invariant)
    }
    __syncthreads();
    int w = t >> 6, lane = t & 63;
    for (int slot = w; slot < 64; slot += 4) {
      f16* dst = A16 + ((size_t)b*64 + slot)*1024 + lane*8;
      if (slot < K_) {
        const float* src = emb + ((size_t)b*N_ + sidx[slot])*D_ + lane*8;
        float4 v0 = ((const float4*)src)[0];
        float4 v1 = ((const float4*)src)[1];
        float s = v0.x*v0.x + v0.y*v0.y + v0.z*v0.z + v0.w*v0.w
                + v1.x*v1.x + v1.y*v1.y + v1.z*v1.z + v1.w*v1.w;
        #pragma unroll
        for (int off = 32; off > 0; off >>= 1) s += __shfl_xor(s, off);
        float inv = 1.0f / (sqrtf(s) + 1e-8f);
        half8 o;
        o[0]=(f16)(v0.x*inv); o[1]=(f16)(v0.y*inv); o[2]=(f16)(v0.z*inv); o[3]=(f16)(v0.w*inv);
        o[4]=(f16)(v1.x*inv); o[5]=(f16)(v1.y*inv); o[6]=(f16)(v1.z*inv); o[7]=(f16)(v1.w*inv);
        *(uint4*)dst = *(uint4*)&o;
      } else {
        uint4 z; z.x=0u; z.y=0u; z.z=0u; z.w=0u;
        *(uint4*)dst = z;   // pad rows zero
      }
    }
  } else {                              // zero csum(512)+css(512), contiguous
    float4 z; z.x=0.f; z.y=0.f; z.z=0.f; z.w=0.f;
    ((float4*)csum)[t] = z;
  }
}

// ---------- gemm1: A16[:,512:1024] = A16[:,0:512] @ W1_16^T + b1 + stats ----
// 128x128 tile, BK=32, waves 2x2 (each 64x64): 8 ds_read : 16 MFMA, swizzled.
__launch_bounds__(256)
__global__ void gemm1_kernel(const f16* __restrict__ A16, const f16* __restrict__ W1_16,
                             const float* __restrict__ b1, f16* __restrict__ Aout,
                             float* __restrict__ csum, float* __restrict__ css) {
  __shared__ f16 sA[128*32];
  __shared__ f16 sB[128*32];
  __shared__ float sSum[4][64], sSS[4][64];
  int t = threadIdx.x;
  int n0 = blockIdx.x * 128;
  int m0 = blockIdx.y * 128;
  int lane = t & 63, w = t >> 6, lm = lane & 15, quad = lane >> 4;
  int rh = w & 1, ch = w >> 1;          // wave -> (row-half, col-half)
  floatx4 acc[4][4] = {};
  const f16* Ab = A16 + (size_t)m0*1024;
  const f16* Bb = W1_16 + (size_t)n0*512;
  int sw = (quad ^ ((lm >> 1) & 3)) * 8;   // swizzled chunk offset for reads
  for (int k0 = 0; k0 < 512; k0 += 32) {
    stage128(Ab + k0, 1024, sA, w, lane);
    stage128(Bb + k0, 512,  sB, w, lane);
    __syncthreads();
    half8 a[4], bf[4];
    #pragma unroll
    for (int i = 0; i < 4; ++i) a[i]  = *(const half8*)&sA[(rh*64 + i*16 + lm)*32 + sw];
    #pragma unroll
    for (int j = 0; j < 4; ++j) bf[j] = *(const half8*)&sB[(ch*64 + j*16 + lm)*32 + sw];
    #pragma unroll
    for (int i = 0; i < 4; ++i)
      #pragma unroll
      for (int j = 0; j < 4; ++j)
        acc[i][j] = __builtin_amdgcn_mfma_f32_16x16x32_f16(a[i], bf[j], acc[i][j], 0, 0, 0);
    __syncthreads();
  }
  // epilogue: write pre-BN h into A16 right half, masked column stats
  #pragma unroll
  for (int j = 0; j < 4; ++j) {
    int col = n0 + ch*64 + j*16 + lm;
    float bias = b1[col];
    float s = 0.f, ss = 0.f;
    #pragma unroll
    for (int i = 0; i < 4; ++i) {
      int rib = i*16 + quad*4;          // row within batch (0..63)
      int row = m0 + rh*64 + rib;
      #pragma unroll
      for (int r = 0; r < 4; ++r) {
        float x = acc[i][j][r] + bias;
        Aout[(size_t)(row + r)*1024 + 512 + col] = (f16)x;
        if (rib + r < K_) { s += x; ss += x*x; }
      }
    }
    s  += __shfl_xor(s, 16);  s  += __shfl_xor(s, 32);
    ss += __shfl_xor(ss, 16); ss += __shfl_xor(ss, 32);
    if (lane < 16) { sSum[w][j*16 + lm] = s; sSS[w][j*16 + lm] = ss; }
  }
  __syncthreads();
  if (t < 128) {
    int wp = (t >> 6) * 2, ci = t & 63;
    atomicAdd(&csum[n0 + t], sSum[wp][ci] + sSum[wp+1][ci]);
    atomicAdd(&css[n0 + t],  sSS[wp][ci]  + sSS[wp+1][ci]);
  }
}

// ---------- bnrelu (in place on A16 right half): x -> relu(x*sc + sh) --------
__global__ void bnrelu_kernel(f16* __restrict__ A16, const float* __restrict__ csum,
                              const float* __restrict__ css, const float* __restrict__ gamma,
                              const float* __restrict__ beta) {
  __shared__ float sSc[H_], sSh[H_];
  int t = threadIdx.x;
  for (int j = t; j < H_; j += 256) {
    float mu  = csum[j] * (1.0f/M_);
    float var = css[j] * (1.0f/M_) - mu*mu;
    float sc  = gamma[j] * rsqrtf(var + 1e-5f);
    sSc[j] = sc;
    sSh[j] = beta[j] - mu*sc;
  }
  __syncthreads();
  int r0 = blockIdx.x * 16;
  #pragma unroll
  for (int i = 0; i < 4; ++i) {
    int seg = t + 256*i;                 // 16 rows x 64 col-segments
    int row = r0 + (seg >> 6);
    int c0  = (seg & 63) * 8;
    f16* p = A16 + (size_t)row*1024 + 512 + c0;
    if ((row & 63) >= K_) {
      uint4 z; z.x=0u; z.y=0u; z.z=0u; z.w=0u;
      *(uint4*)p = z;                    // pad rows must be zero (had +bias)
    } else {
      half8 hv = *(const half8*)p;
      half8 o;
      #pragma unroll
      for (int k = 0; k < 8; ++k)
        o[k] = (f16)fmaxf((float)hv[k]*sSc[c0+k] + sSh[c0+k], 0.0f);
      *(uint4*)p = *(uint4*)&o;
    }
  }
}

// ---------- fused: C = A16 @ Wcat^T, max over k per batch, + biases ----------
// 128x128 tile (2 batches), BK=32, waves 2x2, swizzled conflict-free LDS.
__launch_bounds__(256)
__global__ void fused_kernel(const f16* __restrict__ A16, const f16* __restrict__ Wcat,
                             const float* __restrict__ bfc, const float* __restrict__ b2,
                             float* __restrict__ out) {
  __shared__ f16 sA[128*32];
  __shared__ f16 sB[128*32];
  __shared__ float sMax[4][64];
  int t = threadIdx.x;
  int e0 = blockIdx.x * 128;
  int bm = blockIdx.y;                  // covers batches 2*bm, 2*bm+1
  int lane = t & 63, w = t >> 6, lm = lane & 15, quad = lane >> 4;
  int rh = w & 1, ch = w >> 1;
  floatx4 acc[4][4] = {};
  const f16* Ab = A16 + (size_t)bm*128*1024;
  const f16* Bb = Wcat + (size_t)e0*1024;
  int sw = (quad ^ ((lm >> 1) & 3)) * 8;
  for (int k0 = 0; k0 < 1024; k0 += 32) {
    stage128(Ab + k0, 1024, sA, w, lane);
    stage128(Bb + k0, 1024, sB, w, lane);
    __syncthreads();
    half8 a[4], bf[4];
    #pragma unroll
    for (int i = 0; i < 4; ++i) a[i]  = *(const half8*)&sA[(rh*64 + i*16 + lm)*32 + sw];
    #pragma unroll
    for (int j = 0; j < 4; ++j) bf[j] = *(const half8*)&sB[(ch*64 + j*16 + lm)*32 + sw];
    #pragma unroll
    for (int i = 0; i < 4; ++i)
      #pragma unroll
      for (int j = 0; j < 4; ++j)
        acc[i][j] = __builtin_amdgcn_mfma_f32_16x16x32_f16(a[i], bf[j], acc[i][j], 0, 0, 0);
    __syncthreads();
  }
  // epilogue: masked max over the 58 real rows of this wave's batch (rh)
  #pragma unroll
  for (int j = 0; j < 4; ++j) {
    float mx = -3.0e38f;
    #pragma unroll
    for (int i = 0; i < 4; ++i) {
      int rib = i*16 + quad*4;
      #pragma unroll
      for (int r = 0; r < 4; ++r)
        if (rib + r < K_) mx = fmaxf(mx, acc[i][j][r]);
    }
    mx = fmaxf(mx, __shfl_xor(mx, 16));
    mx = fmaxf(mx, __shfl_xor(mx, 32));
    if (lane < 16) sMax[w][j*16 + lm] = mx;   // wave w: batch rh, cols ch*64+j*16+lm
  }
  __syncthreads();
  {
    int bb = t >> 7, c = t & 127;       // 2 batches x 128 cols = 256 threads
    float mx = sMax[(c >> 6)*2 + bb][c & 63];
    int e = e0 + c;
    out[((size_t)bm*2 + bb)*E_ + e] = mx + bfc[e] + b2[e];
  }
}

extern "C" void kernel_launch(void* const* d_in, const int* in_sizes, int n_in,
                              void* d_out, int out_size, void* d_ws, size_t ws_size,
                              hipStream_t stream) {
  const float* emb   = (const float*)d_in[0];
  const float* attn  = (const float*)d_in[1];
  const float* Wfc   = (const float*)d_in[2];
  const float* bfc   = (const float*)d_in[3];
  const float* W1    = (const float*)d_in[4];
  const float* b1    = (const float*)d_in[5];
  const float* gamma = (const float*)d_in[6];
  const float* beta  = (const float*)d_in[7];
  const float* W2    = (const float*)d_in[8];
  const float* b2    = (const float*)d_in[9];
  float* out = (float*)d_out;

  char* ws = (char*)d_ws;
  f16*   A16   = (f16*)(ws);                    // 16384*1024*2 = 33,554,432
  f16*   Wcat  = (f16*)(ws + 33554432);         // 1024*1024*2  =  2,097,152
  f16*   W1_16 = (f16*)(ws + 35651584);         //  512*512*2   =    524,288
  float* csum  = (float*)(ws + 36175872);       // 2048
  float* css   = (float*)(ws + 36177920);       // 2048 (contiguous after csum)

  setup_kernel<<<897, 256, 0, stream>>>(Wfc, W2, W1, attn, emb, Wcat, W1_16, A16, csum);
  gemm1_kernel<<<dim3(H_/128, M2_/128), 256, 0, stream>>>(A16, W1_16, b1, A16, csum, css);
  bnrelu_kernel<<<M2_/16, 256, 0, stream>>>(A16, csum, css, gamma, beta);
  fused_kernel<<<dim3(E_/128, M2_/128), 256, 0, stream>>>(A16, Wcat, bfc, b2, out);
}